// Round 16
// baseline (309.843 us; speedup 1.0000x reference)
//
#include <hip/hip_runtime.h>

// ---- problem constants (fixed by the reference) ----
#define NN      100000          // nodes (== 6250 * 16)
#define IN_DIM  128
#define HID     32
#define ODIM    64
#define L1C     288             // layer1: 8*32 rel cols + 32 root cols
#define L2K     288             // layer2 K: 8*32 S2 cols + 32 h cols
#define NWGS    196             // scatter workgroups
#define NCB     784             // coarse buckets (dst >> 7, 128 nodes each)
#define CCAP    40              // per-(wg,cb) capacity (mean 10.4)
#define RECCAP  2304            // per-cb record LDS buffer (mean 2041, +5.8 sigma)
#define G2ST    296             // LDS g2 tile row stride (288 + 8 pad)
#define PST     40              // P LDS row stride (shorts; 80 B: 16B-aligned, good bank spread)
#define HST     40              // HgT LDS row stride (shorts)

using bf16x8 = __attribute__((ext_vector_type(8))) short;
using f32x4  = __attribute__((ext_vector_type(4))) float;

__device__ __forceinline__ float bf2f(short s) {
    unsigned int u = ((unsigned int)(unsigned short)s) << 16;
    float f; __builtin_memcpy(&f, &u, 4); return f;
}
__device__ __forceinline__ short f2bf(float f) {
    unsigned int u; __builtin_memcpy(&u, &f, 4);
    u += 0x7fffu + ((u >> 16) & 1u);   // RNE
    return (short)(u >> 16);
}
__device__ __forceinline__ float ldf(const void* p, int i, int f32) {
    return f32 ? ((const float*)p)[i] : bf2f(((const short*)p)[i]);
}
__device__ __forceinline__ int ldi(const int* p, long long i, int i64) {
    return i64 ? p[2 * i] : p[(int)i];
}

// ---- per-input dtype detection (1024 thr, independent loads) ----
__global__ __launch_bounds__(1024) void detect(const short* __restrict__ x,
                                               const short* __restrict__ W1,
                                               const short* __restrict__ r1,
                                               const short* __restrict__ W2,
                                               const short* __restrict__ r2,
                                               const short* __restrict__ lw,
                                               const int* __restrict__ ei,
                                               const int* __restrict__ et,
                                               int* __restrict__ flags) {
    __shared__ int cnt[8];
    if (threadIdx.x < 8) cnt[threadIdx.x] = 0;
    __syncthreads();
    const short* ptrs[6] = {x, W1, r1, W2, r2, lw};
    const int    nsmp[6] = {1024, 1024, 1024, 1024, 1024, 64};
    int t = threadIdx.x;
#pragma unroll
    for (int j = 0; j < 6; ++j) {
        if (t < nsmp[j]) {
            unsigned int s = (unsigned short)ptrs[j][2 * t];
            unsigned int e = (s >> 7) & 0xFF;
            if (e >= 140u || (e >= 1u && e <= 100u)) atomicAdd(&cnt[j], 1);
        }
    }
    if (t < 128) {
        if (ei[2 * t + 1] != 0) atomicAdd(&cnt[6], 1);
        if (et[2 * t + 1] != 0) atomicAdd(&cnt[7], 1);
    }
    __syncthreads();
    if (t == 0) {
        const int ns[6] = {1024, 1024, 1024, 1024, 1024, 64};
        for (int j = 0; j < 6; ++j) flags[j] = (cnt[j] * 4 > ns[j]) ? 1 : 0;
        flags[6] = (cnt[6] == 0) ? 1 : 0;
        flags[7] = (cnt[7] == 0) ? 1 : 0;
    }
}

// ---- merged weight prep: w1t (36864) | w2ct (18432) | smallc (256) ----
__global__ __launch_bounds__(256) void prep_all(const void* __restrict__ W1,
                                                const void* __restrict__ root1,
                                                const void* __restrict__ W2,
                                                const void* __restrict__ root2,
                                                const short* __restrict__ b1,
                                                const short* __restrict__ b2,
                                                const void* __restrict__ lin_w,
                                                const short* __restrict__ lin_b,
                                                short* __restrict__ w1t,
                                                short* __restrict__ w2ct,
                                                short* __restrict__ smallc,
                                                const int* __restrict__ flags) {
    int gi = blockIdx.x * 256 + threadIdx.x;
    if (gi < L1C * IN_DIM) {
        int c = gi >> 7, f = gi & 127;
        float v;
        if (c < 256) { int r = c >> 5, h = c & 31; v = ldf(W1, (r * IN_DIM + f) * HID + h, flags[1]); }
        else         { v = ldf(root1, f * HID + (c - 256), flags[2]); }
        w1t[c * IN_DIM + f] = f2bf(v);
        return;
    }
    int i2 = gi - L1C * IN_DIM;
    if (i2 < ODIM * L2K) {
        int c = i2 / L2K, k = i2 % L2K;
        float v;
        if (k < 256) { int r = k >> 5, kk = k & 31; v = ldf(W2, (r * HID + kk) * ODIM + c, flags[3]); }
        else         { v = ldf(root2, (k - 256) * ODIM + c, flags[4]); }
        w2ct[c * L2K + k] = f2bf(v);
        return;
    }
    int i3 = i2 - ODIM * L2K;
    if (i3 < 256) {
        if (i3 < 32)        smallc[i3] = b1[i3];
        else if (i3 < 96)   smallc[i3] = b2[i3 - 32];
        else if (i3 < 224)  smallc[i3] = f2bf(ldf(lin_w, i3 - 96, flags[5]));
        else if (i3 < 226)  smallc[i3] = lin_b[i3 - 224];
    }
}

// ---- CSR pass 1: WG-private coarse-bucket scatter (1024 thr) ----
__global__ __launch_bounds__(1024) void scatter_coarse(const int* __restrict__ ei,
                                                       const int* __restrict__ et,
                                                       int* __restrict__ cnt,
                                                       int* __restrict__ seg, int E,
                                                       const int* __restrict__ flags) {
    __shared__ int cur[NCB];
    if (threadIdx.x < NCB) cur[threadIdx.x] = 0;
    __syncthreads();
    int i64 = flags[6], t64 = flags[7];
    int epw = (E + NWGS - 1) / NWGS;
    int lo = blockIdx.x * epw;
    int hi = lo + epw; if (hi > E) hi = E;
    for (int i = lo + threadIdx.x; i < hi; i += 1024) {
        int s = ldi(ei, i, i64);
        int d = ldi(ei, (long long)E + i, i64);
        int r = ldi(et, i, t64);
        int cb = d >> 7;
        int pos = atomicAdd(&cur[cb], 1);
        if (pos < CCAP)
            seg[(cb * NWGS + (int)blockIdx.x) * CCAP + pos] = ((d & 127) << 20) | (s << 3) | r;
    }
    __syncthreads();
    if (threadIdx.x < NCB) {
        int c = cur[threadIdx.x];
        cnt[blockIdx.x * NCB + threadIdx.x] = c < CCAP ? c : CCAP;
    }
}

// ---- CSR pass 2: per-cb totals (784 WGs, wave reduce) ----
__global__ __launch_bounds__(64) void cb_sum(const int* __restrict__ cnt,
                                             int* __restrict__ cbTot) {
    int cb = blockIdx.x, lane = threadIdx.x;
    int t = 0;
    for (int g = lane; g < NWGS; g += 64) t += cnt[g * NCB + cb];
#pragma unroll
    for (int o = 32; o > 0; o >>= 1) t += __shfl_down(t, o, 64);
    if (lane == 0) cbTot[cb] = t;
}

// ---- CSR pass 3: per-cb (128 nodes) LDS sort -> off/inv_deg + packed ----
// gbase computed in-block from cbTot (3 KB, L2-hot). off[NN]=E via node==NN.
// packed = (dst&15)<<24 | src<<3 | rel
__global__ __launch_bounds__(256) void build_cb(const int* __restrict__ cnt,
                                                const int* __restrict__ seg,
                                                const int* __restrict__ cbTot,
                                                int* __restrict__ off,
                                                float* __restrict__ inv_deg,
                                                int* __restrict__ packed) {
    __shared__ int cntl[NWGS], soff[NWGS];
    __shared__ int recs[RECCAP];
    __shared__ int degl[128], basel[128], kcur[128];
    __shared__ int stmp[256];
    __shared__ int gbase_s;
    int cb = blockIdx.x, tid = threadIdx.x;
    {
        int part = 0;
        for (int j = tid; j < cb; j += 256) part += cbTot[j];
        stmp[tid] = part; __syncthreads();
        for (int o = 128; o > 0; o >>= 1) {
            if (tid < o) stmp[tid] += stmp[tid + o];
            __syncthreads();
        }
        if (tid == 0) gbase_s = stmp[0];
        __syncthreads();
    }
    if (tid < NWGS) cntl[tid] = cnt[tid * NCB + cb];
    if (tid < 128) degl[tid] = 0;
    __syncthreads();
    int v = (tid < NWGS) ? cntl[tid] : 0;
    stmp[tid] = v; __syncthreads();
    for (int o = 1; o < 256; o <<= 1) {
        int u = (tid >= o) ? stmp[tid - o] : 0;
        __syncthreads();
        stmp[tid] += u;
        __syncthreads();
    }
    if (tid < NWGS) soff[tid] = stmp[tid] - v;
    int tot = stmp[255]; if (tot > RECCAP) tot = RECCAP;
    __syncthreads();
    int wave = tid >> 6, lane = tid & 63;
    for (int g = wave; g < NWGS; g += 4) {
        int c = cntl[g], b = soff[g];
        const int* sp = seg + (cb * NWGS + g) * CCAP;
        for (int e = lane; e < c; e += 64)
            if (b + e < RECCAP) recs[b + e] = sp[e];
    }
    __syncthreads();
    for (int i = tid; i < tot; i += 256) atomicAdd(&degl[recs[i] >> 20], 1);
    __syncthreads();
    int dv = (tid < 128) ? degl[tid] : 0;
    stmp[tid] = dv; __syncthreads();
    for (int o = 1; o < 128; o <<= 1) {
        int u = (tid >= o) ? stmp[tid - o] : 0;
        __syncthreads();
        stmp[tid] += u;
        __syncthreads();
    }
    int gbase = gbase_s;
    if (tid < 128) {
        int excl = stmp[tid] - dv;
        basel[tid] = excl;
        kcur[tid] = 0;
        int node = cb * 128 + tid;
        if (node <= NN) {
            off[node] = gbase + excl;    // node==NN -> off[NN] = E
            if (node < NN) inv_deg[node] = 1.0f / (float)(dv > 1 ? dv : 1);
        }
    }
    __syncthreads();
    for (int i = tid; i < tot; i += 256) {
        int rec = recs[i];
        int n = rec >> 20;
        int p = atomicAdd(&kcur[n], 1);
        packed[gbase + basel[n] + p] = ((n & 15) << 24) | (rec & 0xFFFFF);
    }
}

// ---- GEMM1: [N,128] x w1t[288,128]^T -> xw [N,288] bf16; 64 rows/wave
__global__ __launch_bounds__(256) void gemm1(const void* __restrict__ x,
                                             const short* __restrict__ w1t,
                                             short* __restrict__ xw,
                                             const int* __restrict__ flags) {
    int wave = threadIdx.x >> 6, lane = threadIdx.x & 63;
    int m = lane & 15, quad = lane >> 4;
    int row0 = (blockIdx.x * 4 + wave) * 64;
    if (row0 >= NN) return;

    bf16x8 a[4][4];
    int fp32 = flags[0];
#pragma unroll
    for (int t = 0; t < 4; ++t) {
        int row = row0 + t * 16 + m;
        int rc = row < NN ? row : NN - 1;
        if (fp32) {
            const float* xr = (const float*)x + rc * IN_DIM + quad * 8;
#pragma unroll
            for (int kt = 0; kt < 4; ++kt) {
                const f32x4* q = (const f32x4*)(xr + kt * 32);
                f32x4 u0 = q[0], u1 = q[1];
                bf16x8 tt;
                tt[0] = f2bf(u0[0]); tt[1] = f2bf(u0[1]); tt[2] = f2bf(u0[2]); tt[3] = f2bf(u0[3]);
                tt[4] = f2bf(u1[0]); tt[5] = f2bf(u1[1]); tt[6] = f2bf(u1[2]); tt[7] = f2bf(u1[3]);
                a[t][kt] = tt;
            }
        } else {
            const short* xr = (const short*)x + rc * IN_DIM + quad * 8;
#pragma unroll
            for (int kt = 0; kt < 4; ++kt) a[t][kt] = *(const bf16x8*)(xr + kt * 32);
        }
    }

    for (int ct = 0; ct < 18; ++ct) {
        const short* wp = w1t + (ct * 16 + m) * IN_DIM + quad * 8;
        bf16x8 b[4];
#pragma unroll
        for (int kt = 0; kt < 4; ++kt) b[kt] = *(const bf16x8*)(wp + kt * 32);
#pragma unroll
        for (int t = 0; t < 4; ++t) {
            f32x4 acc = {0.f, 0.f, 0.f, 0.f};
#pragma unroll
            for (int kt = 0; kt < 4; ++kt)
                acc = __builtin_amdgcn_mfma_f32_16x16x32_bf16(a[t][kt], b[kt], acc, 0, 0, 0);
#pragma unroll
            for (int i = 0; i < 4; ++i) {
                int r = row0 + t * 16 + quad * 4 + i;
                if (r < NN) xw[r * L1C + ct * 16 + m] = f2bf(acc[i]);
            }
        }
    }
}

// ---- layer-1 aggregation: 32 lanes/node, unroll-8 gathers -> h (ReLU'd)
__global__ __launch_bounds__(256) void agg1(const short* __restrict__ xw,
                                            const int* __restrict__ off,
                                            const int* __restrict__ packed,
                                            const float* __restrict__ inv_deg,
                                            const short* __restrict__ smallc,
                                            short* __restrict__ h) {
    int lane = threadIdx.x & 31;
    int node = blockIdx.x * 8 + (threadIdx.x >> 5);
    if (node >= NN) return;
    int s = off[node], e = off[node + 1];
    float acc = 0.f;
    int i = s;
    for (; i + 7 < e; i += 8) {
        int pk0 = packed[i],     pk1 = packed[i + 1], pk2 = packed[i + 2], pk3 = packed[i + 3];
        int pk4 = packed[i + 4], pk5 = packed[i + 5], pk6 = packed[i + 6], pk7 = packed[i + 7];
        float v0 = bf2f(xw[((pk0 >> 3) & 0x1FFFF) * L1C + (pk0 & 7) * 32 + lane]);
        float v1 = bf2f(xw[((pk1 >> 3) & 0x1FFFF) * L1C + (pk1 & 7) * 32 + lane]);
        float v2 = bf2f(xw[((pk2 >> 3) & 0x1FFFF) * L1C + (pk2 & 7) * 32 + lane]);
        float v3 = bf2f(xw[((pk3 >> 3) & 0x1FFFF) * L1C + (pk3 & 7) * 32 + lane]);
        float v4 = bf2f(xw[((pk4 >> 3) & 0x1FFFF) * L1C + (pk4 & 7) * 32 + lane]);
        float v5 = bf2f(xw[((pk5 >> 3) & 0x1FFFF) * L1C + (pk5 & 7) * 32 + lane]);
        float v6 = bf2f(xw[((pk6 >> 3) & 0x1FFFF) * L1C + (pk6 & 7) * 32 + lane]);
        float v7 = bf2f(xw[((pk7 >> 3) & 0x1FFFF) * L1C + (pk7 & 7) * 32 + lane]);
        acc += ((v0 + v1) + (v2 + v3)) + ((v4 + v5) + (v6 + v7));
    }
    for (; i + 3 < e; i += 4) {
        int pk0 = packed[i], pk1 = packed[i + 1], pk2 = packed[i + 2], pk3 = packed[i + 3];
        float v0 = bf2f(xw[((pk0 >> 3) & 0x1FFFF) * L1C + (pk0 & 7) * 32 + lane]);
        float v1 = bf2f(xw[((pk1 >> 3) & 0x1FFFF) * L1C + (pk1 & 7) * 32 + lane]);
        float v2 = bf2f(xw[((pk2 >> 3) & 0x1FFFF) * L1C + (pk2 & 7) * 32 + lane]);
        float v3 = bf2f(xw[((pk3 >> 3) & 0x1FFFF) * L1C + (pk3 & 7) * 32 + lane]);
        acc += (v0 + v1) + (v2 + v3);
    }
    for (; i < e; ++i) {
        int pk = packed[i];
        acc += bf2f(xw[((pk >> 3) & 0x1FFFF) * L1C + (pk & 7) * 32 + lane]);
    }
    float v = acc * inv_deg[node] + bf2f(xw[node * L1C + 256 + lane]) + bf2f(smallc[lane]);
    h[node * HID + lane] = f2bf(v > 0.f ? v : 0.f);
}

// ---- fused layer-2: MFMA-P single-chunk (round-14 form) with LDS aliasing ----
// Pl/HgT arena is dead after the gather loop; g2l reuses it -> ~13.3 KB total
// (was 23 KB), lifting blocks/CU toward the 8-block thread cap.
__global__ __launch_bounds__(256) void agg2_fused(const short* __restrict__ h,
                                                  const int* __restrict__ off,
                                                  const int* __restrict__ packed,
                                                  const float* __restrict__ inv_deg,
                                                  const short* __restrict__ w2ct,
                                                  const short* __restrict__ smallc,
                                                  float* __restrict__ out) {
    __shared__ __align__(16) char arena[128 * PST * 2 + 32 * HST * 2];  // 12.8 KB
    short* Pl  = (short*)arena;                    // 128*PST shorts (10.0 KB)
    short* HgT = (short*)arena + 128 * PST;        // 32*HST shorts (2.5 KB)
    short* g2l = (short*)arena;                    // aliases Pl+HgT after loop (9.25 KB)
    __shared__ float red[4][16][2];
    __shared__ float invl[16];
    int tid = threadIdx.x;
    int row0 = blockIdx.x * 16;                       // NN % 16 == 0
    if (tid < 16) invl[tid] = inv_deg[row0 + tid];
    int st = off[row0], en = off[row0 + 16];

    int wave = tid >> 6, lane = tid & 63;
    int m15 = lane & 15, quad = lane >> 4;
    int e = tid & 31;         // edge slot 0..31 (conflict-free HgT mapping)
    int part = tid >> 5;      // dim group: 4 dims each, 8 groups

    // zero P once
    {
        uint4 z = {0, 0, 0, 0};
        uint4* pz = (uint4*)Pl;
#pragma unroll
        for (int j = 0; j < 2; ++j) pz[tid + j * 256] = z;
        if (tid < 128) pz[tid + 512] = z;
    }

    f32x4 acc00 = {0,0,0,0}, acc01 = {0,0,0,0}, acc10 = {0,0,0,0}, acc11 = {0,0,0,0};
    int prevrow = -1;

    for (int c0 = st; c0 < en; c0 += 32) {
        int idx = c0 + e;
        int pk = (idx < en) ? packed[idx] : 0;
        int src = (pk >> 3) & 0x1FFFF;
        uint2 hv = *(const uint2*)(h + src * HID + part * 4);
        __syncthreads();
        if (tid < 32 && prevrow >= 0) Pl[prevrow * PST + e] = 0;   // self-clear
        HgT[(part * 4 + 0) * HST + e] = (short)(hv.x & 0xFFFF);
        HgT[(part * 4 + 1) * HST + e] = (short)(hv.x >> 16);
        HgT[(part * 4 + 2) * HST + e] = (short)(hv.y & 0xFFFF);
        HgT[(part * 4 + 3) * HST + e] = (short)(hv.y >> 16);
        if (tid < 32) {
            if (idx < en) {
                int row = ((pk >> 24) & 15) * 8 + (pk & 7);
                Pl[row * PST + e] = (short)0x3F80;       // bf16 1.0
                prevrow = row;
            } else prevrow = -1;
        }
        __syncthreads();
        bf16x8 a0 = *(const bf16x8*)(&HgT[m15 * HST + quad * 8]);
        bf16x8 a1 = *(const bf16x8*)(&HgT[(m15 + 16) * HST + quad * 8]);
        bf16x8 b0 = *(const bf16x8*)(&Pl[((wave * 2 + 0) * 16 + m15) * PST + quad * 8]);
        bf16x8 b1 = *(const bf16x8*)(&Pl[((wave * 2 + 1) * 16 + m15) * PST + quad * 8]);
        acc00 = __builtin_amdgcn_mfma_f32_16x16x32_bf16(a0, b0, acc00, 0, 0, 0);
        acc10 = __builtin_amdgcn_mfma_f32_16x16x32_bf16(a1, b0, acc10, 0, 0, 0);
        acc01 = __builtin_amdgcn_mfma_f32_16x16x32_bf16(a0, b1, acc01, 0, 0, 0);
        acc11 = __builtin_amdgcn_mfma_f32_16x16x32_bf16(a1, b1, acc11, 0, 0, 0);
    }
    __syncthreads();   // Pl/HgT dead; arena becomes g2l

    // epilogue: acc -> g2l (scaled, bf16). D: col(lane&15)=noderel, row(quad*4+i)=dim
    {
        int nr0 = (wave * 2 + 0) * 16 + m15;
        int nr1 = (wave * 2 + 1) * 16 + m15;
        float sc0 = invl[nr0 >> 3], sc1 = invl[nr1 >> 3];
        int d0 = quad * 4;
#pragma unroll
        for (int i = 0; i < 4; ++i) {
            g2l[(nr0 >> 3) * G2ST + (nr0 & 7) * 32 + d0 + i]      = f2bf(acc00[i] * sc0);
            g2l[(nr0 >> 3) * G2ST + (nr0 & 7) * 32 + 16 + d0 + i] = f2bf(acc10[i] * sc0);
            g2l[(nr1 >> 3) * G2ST + (nr1 & 7) * 32 + d0 + i]      = f2bf(acc01[i] * sc1);
            g2l[(nr1 >> 3) * G2ST + (nr1 & 7) * 32 + 16 + d0 + i] = f2bf(acc11[i] * sc1);
        }
    }
    for (int j = tid; j < 16 * 32; j += 256) {
        int node = j >> 5, d = j & 31;
        g2l[node * G2ST + 256 + d] = h[(row0 + node) * HID + d];
    }
    __syncthreads();

    // phase B: 4 waves, wave = 16-col block; MFMA over K=288 from LDS
    const short* wp = w2ct + (wave * 16 + m15) * L2K + quad * 8;
    bf16x8 a[9], b[9];
#pragma unroll
    for (int kt = 0; kt < 9; ++kt) {
        b[kt] = *(const bf16x8*)(wp + kt * 32);
        a[kt] = *(const bf16x8*)(&g2l[m15 * G2ST + quad * 8 + kt * 32]);
    }
    f32x4 acc = {0.f, 0.f, 0.f, 0.f};
#pragma unroll
    for (int kt = 0; kt < 9; ++kt)
        acc = __builtin_amdgcn_mfma_f32_16x16x32_bf16(a[kt], b[kt], acc, 0, 0, 0);

    int c = wave * 16 + m15;
    float lw0 = bf2f(smallc[96 + c * 2 + 0]);
    float lw1 = bf2f(smallc[96 + c * 2 + 1]);
    float b2c = bf2f(smallc[32 + c]);
    float pr0[4], pr1[4];
#pragma unroll
    for (int i = 0; i < 4; ++i) {
        float v = acc[i] + b2c;
        pr0[i] = v * lw0;
        pr1[i] = v * lw1;
    }
#pragma unroll
    for (int o = 1; o < 16; o <<= 1) {
#pragma unroll
        for (int i = 0; i < 4; ++i) {
            pr0[i] += __shfl_xor(pr0[i], o, 64);
            pr1[i] += __shfl_xor(pr1[i], o, 64);
        }
    }
    if (m15 == 0) {
#pragma unroll
        for (int i = 0; i < 4; ++i) {
            red[wave][quad * 4 + i][0] = pr0[i];
            red[wave][quad * 4 + i][1] = pr1[i];
        }
    }
    __syncthreads();
    if (tid < 32) {
        int row = tid >> 1, j = tid & 1;
        float v = red[0][row][j] + red[1][row][j] + red[2][row][j] + red[3][row][j]
                + bf2f(smallc[224 + j]);
        out[(row0 + row) * 2 + j] = v;
    }
}

extern "C" void kernel_launch(void* const* d_in, const int* in_sizes, int n_in,
                              void* d_out, int out_size, void* d_ws, size_t ws_size,
                              hipStream_t stream) {
    const void* x     = d_in[0];
    const int*  ei    = (const int*)d_in[1];
    const int*  etype = (const int*)d_in[2];
    const void* W1    = d_in[3];
    const void* root1 = d_in[4];
    const void* b1    = d_in[5];
    const void* W2    = d_in[6];
    const void* root2 = d_in[7];
    const void* b2    = d_in[8];
    const void* lin_w = d_in[9];
    const void* lin_b = d_in[10];
    float* out = (float*)d_out;          // fp32 output (verified round 4)

    const int E = in_sizes[2];          // 1,600,000

    // workspace carve (256B aligned). Peak ~100 MB.
    char* p = (char*)d_ws;
    auto alloc = [&](size_t bytes) { char* r = p; p += (bytes + 255) & ~(size_t)255; return (void*)r; };
    int*   flags   = (int*)  alloc(256);
    int*   off     = (int*)  alloc((size_t)(NN + 1) * 4);
    float* inv_deg = (float*)alloc((size_t)NN * 4);
    int*   packed  = (int*)  alloc((size_t)E * 4);
    int*   cnt     = (int*)  alloc((size_t)NWGS * NCB * 4);
    int*   cbTot   = (int*)  alloc((size_t)NCB * 4);
    int*   seg     = (int*)  alloc((size_t)NCB * NWGS * CCAP * 4);   // 24.6 MB
    short* w1t     = (short*)alloc((size_t)L1C * IN_DIM * 2);
    short* w2ct    = (short*)alloc((size_t)ODIM * L2K * 2);
    short* smallc  = (short*)alloc(256 * 2);
    short* h       = (short*)alloc((size_t)NN * HID * 2);
    short* xw1     = (short*)alloc((size_t)NN * L1C * 2);            // 57.6 MB

    detect<<<1, 1024, 0, stream>>>((const short*)x, (const short*)W1, (const short*)root1,
                                   (const short*)W2, (const short*)root2, (const short*)lin_w,
                                   ei, etype, flags);
    const int prep_items = L1C * IN_DIM + ODIM * L2K + 256;
    prep_all<<<(prep_items + 255) / 256, 256, 0, stream>>>(W1, root1, W2, root2,
                                                           (const short*)b1, (const short*)b2,
                                                           lin_w, (const short*)lin_b,
                                                           w1t, w2ct, smallc, flags);

    scatter_coarse<<<NWGS, 1024, 0, stream>>>(ei, etype, cnt, seg, E, flags);
    cb_sum<<<NCB, 64, 0, stream>>>(cnt, cbTot);
    build_cb<<<NCB, 256, 0, stream>>>(cnt, seg, cbTot, off, inv_deg, packed);

    gemm1<<<((NN + 63) / 64 + 3) / 4, 256, 0, stream>>>(x, w1t, xw1, flags);
    agg1<<<(NN + 7) / 8, 256, 0, stream>>>(xw1, off, packed, inv_deg, smallc, h);
    agg2_fused<<<NN / 16, 256, 0, stream>>>(h, off, packed, inv_deg, w2ct, smallc, out);
}

// Round 17
// 286.237 us; speedup vs baseline: 1.0825x; 1.0825x over previous
//
#include <hip/hip_runtime.h>

// ---- problem constants (fixed by the reference) ----
#define NN      100000          // nodes (== 6250 * 16)
#define IN_DIM  128
#define HID     32
#define ODIM    64
#define L1C     288             // layer1: 8*32 rel cols + 32 root cols
#define L2K     288             // layer2 K: 8*32 S2 cols + 32 h cols
#define NWGS    196             // scatter workgroups
#define NCB     784             // coarse buckets (dst >> 7, 128 nodes each)
#define CCAP    40              // per-(wg,cb) capacity (mean 10.4)
#define RECCAP  2304            // per-cb record LDS buffer (mean 2041, +5.8 sigma)
#define G2ST    296             // LDS g2 tile row stride (288 + 8 pad)
#define PST     40              // P LDS row stride (shorts; 80 B: 16B-aligned)
#define HST     40              // HgT LDS row stride (shorts)
#define PKCAP   512             // per-tile packed prefetch capacity (mean 256, +16 sigma)

using bf16x8 = __attribute__((ext_vector_type(8))) short;
using f32x4  = __attribute__((ext_vector_type(4))) float;

__device__ __forceinline__ float bf2f(short s) {
    unsigned int u = ((unsigned int)(unsigned short)s) << 16;
    float f; __builtin_memcpy(&f, &u, 4); return f;
}
__device__ __forceinline__ short f2bf(float f) {
    unsigned int u; __builtin_memcpy(&u, &f, 4);
    u += 0x7fffu + ((u >> 16) & 1u);   // RNE
    return (short)(u >> 16);
}
__device__ __forceinline__ float ldf(const void* p, int i, int f32) {
    return f32 ? ((const float*)p)[i] : bf2f(((const short*)p)[i]);
}
__device__ __forceinline__ int ldi(const int* p, long long i, int i64) {
    return i64 ? p[2 * i] : p[(int)i];
}

// ---- per-input dtype detection (1024 thr, independent loads) ----
__global__ __launch_bounds__(1024) void detect(const short* __restrict__ x,
                                               const short* __restrict__ W1,
                                               const short* __restrict__ r1,
                                               const short* __restrict__ W2,
                                               const short* __restrict__ r2,
                                               const short* __restrict__ lw,
                                               const int* __restrict__ ei,
                                               const int* __restrict__ et,
                                               int* __restrict__ flags) {
    __shared__ int cnt[8];
    if (threadIdx.x < 8) cnt[threadIdx.x] = 0;
    __syncthreads();
    const short* ptrs[6] = {x, W1, r1, W2, r2, lw};
    const int    nsmp[6] = {1024, 1024, 1024, 1024, 1024, 64};
    int t = threadIdx.x;
#pragma unroll
    for (int j = 0; j < 6; ++j) {
        if (t < nsmp[j]) {
            unsigned int s = (unsigned short)ptrs[j][2 * t];
            unsigned int e = (s >> 7) & 0xFF;
            if (e >= 140u || (e >= 1u && e <= 100u)) atomicAdd(&cnt[j], 1);
        }
    }
    if (t < 128) {
        if (ei[2 * t + 1] != 0) atomicAdd(&cnt[6], 1);
        if (et[2 * t + 1] != 0) atomicAdd(&cnt[7], 1);
    }
    __syncthreads();
    if (t == 0) {
        const int ns[6] = {1024, 1024, 1024, 1024, 1024, 64};
        for (int j = 0; j < 6; ++j) flags[j] = (cnt[j] * 4 > ns[j]) ? 1 : 0;
        flags[6] = (cnt[6] == 0) ? 1 : 0;
        flags[7] = (cnt[7] == 0) ? 1 : 0;
    }
}

// ---- merged weight prep: w1t (36864) | w2ct (18432) | smallc (256) ----
__global__ __launch_bounds__(256) void prep_all(const void* __restrict__ W1,
                                                const void* __restrict__ root1,
                                                const void* __restrict__ W2,
                                                const void* __restrict__ root2,
                                                const short* __restrict__ b1,
                                                const short* __restrict__ b2,
                                                const void* __restrict__ lin_w,
                                                const short* __restrict__ lin_b,
                                                short* __restrict__ w1t,
                                                short* __restrict__ w2ct,
                                                short* __restrict__ smallc,
                                                const int* __restrict__ flags) {
    int gi = blockIdx.x * 256 + threadIdx.x;
    if (gi < L1C * IN_DIM) {
        int c = gi >> 7, f = gi & 127;
        float v;
        if (c < 256) { int r = c >> 5, h = c & 31; v = ldf(W1, (r * IN_DIM + f) * HID + h, flags[1]); }
        else         { v = ldf(root1, f * HID + (c - 256), flags[2]); }
        w1t[c * IN_DIM + f] = f2bf(v);
        return;
    }
    int i2 = gi - L1C * IN_DIM;
    if (i2 < ODIM * L2K) {
        int c = i2 / L2K, k = i2 % L2K;
        float v;
        if (k < 256) { int r = k >> 5, kk = k & 31; v = ldf(W2, (r * HID + kk) * ODIM + c, flags[3]); }
        else         { v = ldf(root2, (k - 256) * ODIM + c, flags[4]); }
        w2ct[c * L2K + k] = f2bf(v);
        return;
    }
    int i3 = i2 - ODIM * L2K;
    if (i3 < 256) {
        if (i3 < 32)        smallc[i3] = b1[i3];
        else if (i3 < 96)   smallc[i3] = b2[i3 - 32];
        else if (i3 < 224)  smallc[i3] = f2bf(ldf(lin_w, i3 - 96, flags[5]));
        else if (i3 < 226)  smallc[i3] = lin_b[i3 - 224];
    }
}

// ---- CSR pass 1: WG-private coarse-bucket scatter (1024 thr) ----
__global__ __launch_bounds__(1024) void scatter_coarse(const int* __restrict__ ei,
                                                       const int* __restrict__ et,
                                                       int* __restrict__ cnt,
                                                       int* __restrict__ seg, int E,
                                                       const int* __restrict__ flags) {
    __shared__ int cur[NCB];
    if (threadIdx.x < NCB) cur[threadIdx.x] = 0;
    __syncthreads();
    int i64 = flags[6], t64 = flags[7];
    int epw = (E + NWGS - 1) / NWGS;
    int lo = blockIdx.x * epw;
    int hi = lo + epw; if (hi > E) hi = E;
    for (int i = lo + threadIdx.x; i < hi; i += 1024) {
        int s = ldi(ei, i, i64);
        int d = ldi(ei, (long long)E + i, i64);
        int r = ldi(et, i, t64);
        int cb = d >> 7;
        int pos = atomicAdd(&cur[cb], 1);
        if (pos < CCAP)
            seg[(cb * NWGS + (int)blockIdx.x) * CCAP + pos] = ((d & 127) << 20) | (s << 3) | r;
    }
    __syncthreads();
    if (threadIdx.x < NCB) {
        int c = cur[threadIdx.x];
        cnt[blockIdx.x * NCB + threadIdx.x] = c < CCAP ? c : CCAP;
    }
}

// ---- CSR pass 2: per-cb totals (784 WGs, wave reduce) ----
__global__ __launch_bounds__(64) void cb_sum(const int* __restrict__ cnt,
                                             int* __restrict__ cbTot) {
    int cb = blockIdx.x, lane = threadIdx.x;
    int t = 0;
    for (int g = lane; g < NWGS; g += 64) t += cnt[g * NCB + cb];
#pragma unroll
    for (int o = 32; o > 0; o >>= 1) t += __shfl_down(t, o, 64);
    if (lane == 0) cbTot[cb] = t;
}

// ---- CSR pass 3: per-cb (128 nodes) LDS sort -> off/inv_deg + packed ----
// packed = (dst&15)<<24 | src<<3 | rel
__global__ __launch_bounds__(256) void build_cb(const int* __restrict__ cnt,
                                                const int* __restrict__ seg,
                                                const int* __restrict__ cbTot,
                                                int* __restrict__ off,
                                                float* __restrict__ inv_deg,
                                                int* __restrict__ packed) {
    __shared__ int cntl[NWGS], soff[NWGS];
    __shared__ int recs[RECCAP];
    __shared__ int degl[128], basel[128], kcur[128];
    __shared__ int stmp[256];
    __shared__ int gbase_s;
    int cb = blockIdx.x, tid = threadIdx.x;
    {
        int part = 0;
        for (int j = tid; j < cb; j += 256) part += cbTot[j];
        stmp[tid] = part; __syncthreads();
        for (int o = 128; o > 0; o >>= 1) {
            if (tid < o) stmp[tid] += stmp[tid + o];
            __syncthreads();
        }
        if (tid == 0) gbase_s = stmp[0];
        __syncthreads();
    }
    if (tid < NWGS) cntl[tid] = cnt[tid * NCB + cb];
    if (tid < 128) degl[tid] = 0;
    __syncthreads();
    int v = (tid < NWGS) ? cntl[tid] : 0;
    stmp[tid] = v; __syncthreads();
    for (int o = 1; o < 256; o <<= 1) {
        int u = (tid >= o) ? stmp[tid - o] : 0;
        __syncthreads();
        stmp[tid] += u;
        __syncthreads();
    }
    if (tid < NWGS) soff[tid] = stmp[tid] - v;
    int tot = stmp[255]; if (tot > RECCAP) tot = RECCAP;
    __syncthreads();
    int wave = tid >> 6, lane = tid & 63;
    for (int g = wave; g < NWGS; g += 4) {
        int c = cntl[g], b = soff[g];
        const int* sp = seg + (cb * NWGS + g) * CCAP;
        for (int e = lane; e < c; e += 64)
            if (b + e < RECCAP) recs[b + e] = sp[e];
    }
    __syncthreads();
    for (int i = tid; i < tot; i += 256) atomicAdd(&degl[recs[i] >> 20], 1);
    __syncthreads();
    int dv = (tid < 128) ? degl[tid] : 0;
    stmp[tid] = dv; __syncthreads();
    for (int o = 1; o < 128; o <<= 1) {
        int u = (tid >= o) ? stmp[tid - o] : 0;
        __syncthreads();
        stmp[tid] += u;
        __syncthreads();
    }
    int gbase = gbase_s;
    if (tid < 128) {
        int excl = stmp[tid] - dv;
        basel[tid] = excl;
        kcur[tid] = 0;
        int node = cb * 128 + tid;
        if (node <= NN) {
            off[node] = gbase + excl;    // node==NN -> off[NN] = E
            if (node < NN) inv_deg[node] = 1.0f / (float)(dv > 1 ? dv : 1);
        }
    }
    __syncthreads();
    for (int i = tid; i < tot; i += 256) {
        int rec = recs[i];
        int n = rec >> 20;
        int p = atomicAdd(&kcur[n], 1);
        packed[gbase + basel[n] + p] = ((n & 15) << 24) | (rec & 0xFFFFF);
    }
}

// ---- GEMM1: [N,128] x w1t[288,128]^T -> xw [N,288] bf16; 64 rows/wave
__global__ __launch_bounds__(256) void gemm1(const void* __restrict__ x,
                                             const short* __restrict__ w1t,
                                             short* __restrict__ xw,
                                             const int* __restrict__ flags) {
    int wave = threadIdx.x >> 6, lane = threadIdx.x & 63;
    int m = lane & 15, quad = lane >> 4;
    int row0 = (blockIdx.x * 4 + wave) * 64;
    if (row0 >= NN) return;

    bf16x8 a[4][4];
    int fp32 = flags[0];
#pragma unroll
    for (int t = 0; t < 4; ++t) {
        int row = row0 + t * 16 + m;
        int rc = row < NN ? row : NN - 1;
        if (fp32) {
            const float* xr = (const float*)x + rc * IN_DIM + quad * 8;
#pragma unroll
            for (int kt = 0; kt < 4; ++kt) {
                const f32x4* q = (const f32x4*)(xr + kt * 32);
                f32x4 u0 = q[0], u1 = q[1];
                bf16x8 tt;
                tt[0] = f2bf(u0[0]); tt[1] = f2bf(u0[1]); tt[2] = f2bf(u0[2]); tt[3] = f2bf(u0[3]);
                tt[4] = f2bf(u1[0]); tt[5] = f2bf(u1[1]); tt[6] = f2bf(u1[2]); tt[7] = f2bf(u1[3]);
                a[t][kt] = tt;
            }
        } else {
            const short* xr = (const short*)x + rc * IN_DIM + quad * 8;
#pragma unroll
            for (int kt = 0; kt < 4; ++kt) a[t][kt] = *(const bf16x8*)(xr + kt * 32);
        }
    }

    for (int ct = 0; ct < 18; ++ct) {
        const short* wp = w1t + (ct * 16 + m) * IN_DIM + quad * 8;
        bf16x8 b[4];
#pragma unroll
        for (int kt = 0; kt < 4; ++kt) b[kt] = *(const bf16x8*)(wp + kt * 32);
#pragma unroll
        for (int t = 0; t < 4; ++t) {
            f32x4 acc = {0.f, 0.f, 0.f, 0.f};
#pragma unroll
            for (int kt = 0; kt < 4; ++kt)
                acc = __builtin_amdgcn_mfma_f32_16x16x32_bf16(a[t][kt], b[kt], acc, 0, 0, 0);
#pragma unroll
            for (int i = 0; i < 4; ++i) {
                int r = row0 + t * 16 + quad * 4 + i;
                if (r < NN) xw[r * L1C + ct * 16 + m] = f2bf(acc[i]);
            }
        }
    }
}

// ---- layer-1 aggregation: 32 lanes/node, unroll-8 gathers -> h (ReLU'd)
__global__ __launch_bounds__(256) void agg1(const short* __restrict__ xw,
                                            const int* __restrict__ off,
                                            const int* __restrict__ packed,
                                            const float* __restrict__ inv_deg,
                                            const short* __restrict__ smallc,
                                            short* __restrict__ h) {
    int lane = threadIdx.x & 31;
    int node = blockIdx.x * 8 + (threadIdx.x >> 5);
    if (node >= NN) return;
    int s = off[node], e = off[node + 1];
    float acc = 0.f;
    int i = s;
    for (; i + 7 < e; i += 8) {
        int pk0 = packed[i],     pk1 = packed[i + 1], pk2 = packed[i + 2], pk3 = packed[i + 3];
        int pk4 = packed[i + 4], pk5 = packed[i + 5], pk6 = packed[i + 6], pk7 = packed[i + 7];
        float v0 = bf2f(xw[((pk0 >> 3) & 0x1FFFF) * L1C + (pk0 & 7) * 32 + lane]);
        float v1 = bf2f(xw[((pk1 >> 3) & 0x1FFFF) * L1C + (pk1 & 7) * 32 + lane]);
        float v2 = bf2f(xw[((pk2 >> 3) & 0x1FFFF) * L1C + (pk2 & 7) * 32 + lane]);
        float v3 = bf2f(xw[((pk3 >> 3) & 0x1FFFF) * L1C + (pk3 & 7) * 32 + lane]);
        float v4 = bf2f(xw[((pk4 >> 3) & 0x1FFFF) * L1C + (pk4 & 7) * 32 + lane]);
        float v5 = bf2f(xw[((pk5 >> 3) & 0x1FFFF) * L1C + (pk5 & 7) * 32 + lane]);
        float v6 = bf2f(xw[((pk6 >> 3) & 0x1FFFF) * L1C + (pk6 & 7) * 32 + lane]);
        float v7 = bf2f(xw[((pk7 >> 3) & 0x1FFFF) * L1C + (pk7 & 7) * 32 + lane]);
        acc += ((v0 + v1) + (v2 + v3)) + ((v4 + v5) + (v6 + v7));
    }
    for (; i + 3 < e; i += 4) {
        int pk0 = packed[i], pk1 = packed[i + 1], pk2 = packed[i + 2], pk3 = packed[i + 3];
        float v0 = bf2f(xw[((pk0 >> 3) & 0x1FFFF) * L1C + (pk0 & 7) * 32 + lane]);
        float v1 = bf2f(xw[((pk1 >> 3) & 0x1FFFF) * L1C + (pk1 & 7) * 32 + lane]);
        float v2 = bf2f(xw[((pk2 >> 3) & 0x1FFFF) * L1C + (pk2 & 7) * 32 + lane]);
        float v3 = bf2f(xw[((pk3 >> 3) & 0x1FFFF) * L1C + (pk3 & 7) * 32 + lane]);
        acc += (v0 + v1) + (v2 + v3);
    }
    for (; i < e; ++i) {
        int pk = packed[i];
        acc += bf2f(xw[((pk >> 3) & 0x1FFFF) * L1C + (pk & 7) * 32 + lane]);
    }
    float v = acc * inv_deg[node] + bf2f(xw[node * L1C + 256 + lane]) + bf2f(smallc[lane]);
    h[node * HID + lane] = f2bf(v > 0.f ? v : 0.f);
}

// ---- fused layer-2: MFMA-P, ping-pong panels (1 barrier/chunk), packed
// prefetched to LDS, h-gather software-pipelined one chunk ahead ----
__global__ __launch_bounds__(256) void agg2_fused(const short* __restrict__ h,
                                                  const int* __restrict__ off,
                                                  const int* __restrict__ packed,
                                                  const float* __restrict__ inv_deg,
                                                  const short* __restrict__ w2ct,
                                                  const short* __restrict__ smallc,
                                                  float* __restrict__ out) {
    __shared__ __align__(16) short Pl[2][128 * PST];   // 20 KB (g2l aliases Pl[0] later)
    __shared__ __align__(16) short HgT[2][32 * HST];   // 5 KB
    __shared__ int pk_l[PKCAP];                        // 2 KB
    __shared__ float red[4][16][2];
    __shared__ float invl[16];
    short* g2l = &Pl[0][0];                            // alias: Pl dead after loop
    int tid = threadIdx.x;
    int row0 = blockIdx.x * 16;                        // NN % 16 == 0
    if (tid < 16) invl[tid] = inv_deg[row0 + tid];
    int st = off[row0], en = off[row0 + 16];
    int tot = en - st;

    int wave = tid >> 6, lane = tid & 63;
    int m15 = lane & 15, quad = lane >> 4;
    int e = tid & 31;         // edge slot 0..31
    int part = tid >> 5;      // dim group: 4 dims each, 8 groups

    // zero both P panels + prefetch packed into LDS (one coalesced pass)
    {
        uint4 z = {0, 0, 0, 0};
        uint4* pz = (uint4*)&Pl[0][0];
#pragma unroll
        for (int j = 0; j < 5; ++j) pz[tid + j * 256] = z;   // 1280 uint4 = both panels
        for (int j = tid; j < tot && j < PKCAP; j += 256) pk_l[j] = packed[st + j];
    }
    __syncthreads();

    f32x4 acc00 = {0,0,0,0}, acc01 = {0,0,0,0}, acc10 = {0,0,0,0}, acc11 = {0,0,0,0};
    int prevrow[2] = {-1, -1};
    int nchunk = (tot + 31) >> 5;

    // preload chunk 0
    int pk = (e < tot) ? ((e < PKCAP) ? pk_l[e] : packed[st + e]) : 0;
    uint2 hv = *(const uint2*)(h + ((pk >> 3) & 0x1FFFF) * HID + part * 4);

    for (int c = 0; c < nchunk; ++c) {
        int p = c & 1;
        int valid = (c * 32 + e) < tot;
        if (tid < 32 && prevrow[p] >= 0) Pl[p][prevrow[p] * PST + e] = 0;  // self-clear
        HgT[p][(part * 4 + 0) * HST + e] = (short)(hv.x & 0xFFFF);
        HgT[p][(part * 4 + 1) * HST + e] = (short)(hv.x >> 16);
        HgT[p][(part * 4 + 2) * HST + e] = (short)(hv.y & 0xFFFF);
        HgT[p][(part * 4 + 3) * HST + e] = (short)(hv.y >> 16);
        if (tid < 32) {
            if (valid) {
                int row = ((pk >> 24) & 15) * 8 + (pk & 7);
                Pl[p][row * PST + e] = (short)0x3F80;      // bf16 1.0
                prevrow[p] = row;
            } else prevrow[p] = -1;
        }
        // prefetch next chunk's edge + h row (overlaps barrier + MFMA below)
        int idx = (c + 1) * 32 + e;
        int pkn = (idx < tot) ? ((idx < PKCAP) ? pk_l[idx] : packed[st + idx]) : 0;
        uint2 hvn = *(const uint2*)(h + ((pkn >> 3) & 0x1FFFF) * HID + part * 4);
        __syncthreads();
        bf16x8 a0 = *(const bf16x8*)(&HgT[p][m15 * HST + quad * 8]);
        bf16x8 a1 = *(const bf16x8*)(&HgT[p][(m15 + 16) * HST + quad * 8]);
        bf16x8 b0 = *(const bf16x8*)(&Pl[p][((wave * 2 + 0) * 16 + m15) * PST + quad * 8]);
        bf16x8 b1 = *(const bf16x8*)(&Pl[p][((wave * 2 + 1) * 16 + m15) * PST + quad * 8]);
        acc00 = __builtin_amdgcn_mfma_f32_16x16x32_bf16(a0, b0, acc00, 0, 0, 0);
        acc10 = __builtin_amdgcn_mfma_f32_16x16x32_bf16(a1, b0, acc10, 0, 0, 0);
        acc01 = __builtin_amdgcn_mfma_f32_16x16x32_bf16(a0, b1, acc01, 0, 0, 0);
        acc11 = __builtin_amdgcn_mfma_f32_16x16x32_bf16(a1, b1, acc11, 0, 0, 0);
        pk = pkn; hv = hvn;
    }
    __syncthreads();   // panels dead; arena becomes g2l

    // epilogue: acc -> g2l (scaled, bf16). D: col(lane&15)=noderel, row(quad*4+i)=dim
    {
        int nr0 = (wave * 2 + 0) * 16 + m15;
        int nr1 = (wave * 2 + 1) * 16 + m15;
        float sc0 = invl[nr0 >> 3], sc1 = invl[nr1 >> 3];
        int d0 = quad * 4;
#pragma unroll
        for (int i = 0; i < 4; ++i) {
            g2l[(nr0 >> 3) * G2ST + (nr0 & 7) * 32 + d0 + i]      = f2bf(acc00[i] * sc0);
            g2l[(nr0 >> 3) * G2ST + (nr0 & 7) * 32 + 16 + d0 + i] = f2bf(acc10[i] * sc0);
            g2l[(nr1 >> 3) * G2ST + (nr1 & 7) * 32 + d0 + i]      = f2bf(acc01[i] * sc1);
            g2l[(nr1 >> 3) * G2ST + (nr1 & 7) * 32 + 16 + d0 + i] = f2bf(acc11[i] * sc1);
        }
    }
    for (int j = tid; j < 16 * 32; j += 256) {
        int node = j >> 5, d = j & 31;
        g2l[node * G2ST + 256 + d] = h[(row0 + node) * HID + d];
    }
    __syncthreads();

    // phase B: 4 waves, wave = 16-col block; MFMA over K=288 from LDS
    const short* wp = w2ct + (wave * 16 + m15) * L2K + quad * 8;
    bf16x8 a[9], b[9];
#pragma unroll
    for (int kt = 0; kt < 9; ++kt) {
        b[kt] = *(const bf16x8*)(wp + kt * 32);
        a[kt] = *(const bf16x8*)(&g2l[m15 * G2ST + quad * 8 + kt * 32]);
    }
    f32x4 acc = {0.f, 0.f, 0.f, 0.f};
#pragma unroll
    for (int kt = 0; kt < 9; ++kt)
        acc = __builtin_amdgcn_mfma_f32_16x16x32_bf16(a[kt], b[kt], acc, 0, 0, 0);

    int c = wave * 16 + m15;
    float lw0 = bf2f(smallc[96 + c * 2 + 0]);
    float lw1 = bf2f(smallc[96 + c * 2 + 1]);
    float b2c = bf2f(smallc[32 + c]);
    float pr0[4], pr1[4];
#pragma unroll
    for (int i = 0; i < 4; ++i) {
        float v = acc[i] + b2c;
        pr0[i] = v * lw0;
        pr1[i] = v * lw1;
    }
#pragma unroll
    for (int o = 1; o < 16; o <<= 1) {
#pragma unroll
        for (int i = 0; i < 4; ++i) {
            pr0[i] += __shfl_xor(pr0[i], o, 64);
            pr1[i] += __shfl_xor(pr1[i], o, 64);
        }
    }
    if (m15 == 0) {
#pragma unroll
        for (int i = 0; i < 4; ++i) {
            red[wave][quad * 4 + i][0] = pr0[i];
            red[wave][quad * 4 + i][1] = pr1[i];
        }
    }
    __syncthreads();
    if (tid < 32) {
        int row = tid >> 1, j = tid & 1;
        float v = red[0][row][j] + red[1][row][j] + red[2][row][j] + red[3][row][j]
                + bf2f(smallc[224 + j]);
        out[(row0 + row) * 2 + j] = v;
    }
}

extern "C" void kernel_launch(void* const* d_in, const int* in_sizes, int n_in,
                              void* d_out, int out_size, void* d_ws, size_t ws_size,
                              hipStream_t stream) {
    const void* x     = d_in[0];
    const int*  ei    = (const int*)d_in[1];
    const int*  etype = (const int*)d_in[2];
    const void* W1    = d_in[3];
    const void* root1 = d_in[4];
    const void* b1    = d_in[5];
    const void* W2    = d_in[6];
    const void* root2 = d_in[7];
    const void* b2    = d_in[8];
    const void* lin_w = d_in[9];
    const void* lin_b = d_in[10];
    float* out = (float*)d_out;          // fp32 output (verified round 4)

    const int E = in_sizes[2];          // 1,600,000

    // workspace carve (256B aligned). Peak ~100 MB.
    char* p = (char*)d_ws;
    auto alloc = [&](size_t bytes) { char* r = p; p += (bytes + 255) & ~(size_t)255; return (void*)r; };
    int*   flags   = (int*)  alloc(256);
    int*   off     = (int*)  alloc((size_t)(NN + 1) * 4);
    float* inv_deg = (float*)alloc((size_t)NN * 4);
    int*   packed  = (int*)  alloc((size_t)E * 4);
    int*   cnt     = (int*)  alloc((size_t)NWGS * NCB * 4);
    int*   cbTot   = (int*)  alloc((size_t)NCB * 4);
    int*   seg     = (int*)  alloc((size_t)NCB * NWGS * CCAP * 4);   // 24.6 MB
    short* w1t     = (short*)alloc((size_t)L1C * IN_DIM * 2);
    short* w2ct    = (short*)alloc((size_t)ODIM * L2K * 2);
    short* smallc  = (short*)alloc(256 * 2);
    short* h       = (short*)alloc((size_t)NN * HID * 2);
    short* xw1     = (short*)alloc((size_t)NN * L1C * 2);            // 57.6 MB

    detect<<<1, 1024, 0, stream>>>((const short*)x, (const short*)W1, (const short*)root1,
                                   (const short*)W2, (const short*)root2, (const short*)lin_w,
                                   ei, etype, flags);
    const int prep_items = L1C * IN_DIM + ODIM * L2K + 256;
    prep_all<<<(prep_items + 255) / 256, 256, 0, stream>>>(W1, root1, W2, root2,
                                                           (const short*)b1, (const short*)b2,
                                                           lin_w, (const short*)lin_b,
                                                           w1t, w2ct, smallc, flags);

    scatter_coarse<<<NWGS, 1024, 0, stream>>>(ei, etype, cnt, seg, E, flags);
    cb_sum<<<NCB, 64, 0, stream>>>(cnt, cbTot);
    build_cb<<<NCB, 256, 0, stream>>>(cnt, seg, cbTot, off, inv_deg, packed);

    gemm1<<<((NN + 63) / 64 + 3) / 4, 256, 0, stream>>>(x, w1t, xw1, flags);
    agg1<<<(NN + 7) / 8, 256, 0, stream>>>(xw1, off, packed, inv_deg, smallc, h);
    agg2_fused<<<NN / 16, 256, 0, stream>>>(h, off, packed, inv_deg, w2ct, smallc, out);
}